// Round 2
// baseline (86.516 us; speedup 1.0000x reference)
//
#include <hip/hip_runtime.h>
#include <hip/hip_bf16.h>

// Segment-wise attention-weighted mean.
//   avg[b][h][d]     = sum_{i in seg b} features[i][d]*att[i][h] / sum att[i][h]
//   weights_sum[b][h] = sum_{i in seg b} att[i][h]
// segment_ids sorted -> segments contiguous. B=64, H=8, D=128, TOTAL=262144.

constexpr int D   = 128;
constexpr int H   = 8;
constexpr int B   = 64;
constexpr int CPS = 32;   // chunk-blocks per segment -> 2048 blocks (8/CU)

// --- kernel 1: find segment start offsets (start[b] .. start[b+1]) ---------
__global__ void seg_bounds_kernel(const int* __restrict__ seg, int total,
                                  int* __restrict__ start) {
    int i = blockIdx.x * blockDim.x + threadIdx.x;
    if (i >= total) return;
    int s = seg[i];
    if (i == 0) {
        for (int b = 0; b <= s; ++b) start[b] = 0;
    } else {
        int p = seg[i - 1];
        for (int b = p + 1; b <= s; ++b) start[b] = i;
    }
    if (i == total - 1) {
        for (int b = s + 1; b <= B; ++b) start[b] = total;
    }
}

// --- kernel 2: accumulate weighted sums into d_out (pre-zeroed) ------------
// 256 threads: thread t owns head h = t>>5 and dims [4*(t&31) .. +4).
// Per row: one float4 feature load (16B/lane, coalesced) + one broadcast att
// load. One atomic flush per block at the end.
__global__ __launch_bounds__(256) void accum_kernel(
        const float4* __restrict__ F,     // features as float4, 32 per row
        const float*  __restrict__ att,   // TOTAL x 8
        const int*    __restrict__ start, // B+1
        float* __restrict__ out) {        // [B*H*D sums | B*H wsums]
    const int b  = blockIdx.x / CPS;
    const int c  = blockIdx.x % CPS;
    const int s0 = start[b], s1 = start[b + 1];
    const int n  = s1 - s0;
    const int chunk = (n + CPS - 1) / CPS;
    int r0 = s0 + c * chunk;
    int r1 = min(r0 + chunk, s1);
    if (r0 >= r1) return;

    const int t  = threadIdx.x;
    const int dq = t & 31;   // which float4 of the row
    const int h  = t >> 5;   // head 0..7

    float a0 = 0.f, a1 = 0.f, a2 = 0.f, a3 = 0.f, w = 0.f;
    #pragma unroll 2
    for (int i = r0; i < r1; ++i) {
        float  a = att[i * H + h];
        float4 f = F[i * (D / 4) + dq];
        a0 = fmaf(f.x, a, a0);
        a1 = fmaf(f.y, a, a1);
        a2 = fmaf(f.z, a, a2);
        a3 = fmaf(f.w, a, a3);
        w += a;
    }

    float* o = out + (b * H + h) * D + dq * 4;
    atomicAdd(o + 0, a0);
    atomicAdd(o + 1, a1);
    atomicAdd(o + 2, a2);
    atomicAdd(o + 3, a3);
    if (dq == 0) atomicAdd(out + B * H * D + b * H + h, w);
}

// --- kernel 3: divide, apply where(denom==0,0) and NaN->1e-5 ---------------
__global__ void finalize_kernel(float* __restrict__ out) {
    int idx = blockIdx.x * blockDim.x + threadIdx.x;
    if (idx >= B * H * D) return;
    int   bh    = idx >> 7;                 // b*H + h
    float denom = out[B * H * D + bh];
    float v     = out[idx];
    float r     = (denom == 0.0f) ? 0.0f : v / denom;
    if (isnan(r)) r = 1e-5f;
    out[idx] = r;
}

extern "C" void kernel_launch(void* const* d_in, const int* in_sizes, int n_in,
                              void* d_out, int out_size, void* d_ws, size_t ws_size,
                              hipStream_t stream) {
    const float* features = (const float*)d_in[0];
    const float* att      = (const float*)d_in[1];
    const int*   seg      = (const int*)d_in[2];
    const int    total    = in_sizes[2];

    int*   start = (int*)d_ws;          // B+1 ints of scratch
    float* out   = (float*)d_out;

    // zero accumulators (memset node is graph-capture legal)
    hipMemsetAsync(d_out, 0, (size_t)out_size * sizeof(float), stream);

    seg_bounds_kernel<<<(total + 255) / 256, 256, 0, stream>>>(seg, total, start);
    accum_kernel<<<B * CPS, 256, 0, stream>>>(
        (const float4*)features, att, start, out);
    finalize_kernel<<<(B * H * D + 255) / 256, 256, 0, stream>>>(out);
}

// Round 3
// 80.422 us; speedup vs baseline: 1.0758x; 1.0758x over previous
//
#include <hip/hip_runtime.h>

// Segment-wise attention-weighted mean.
//   avg[b][h][d]      = sum_{i in seg b} features[i][d]*att[i][h] / sum att[i][h]
//   weights_sum[b][h] = sum_{i in seg b} att[i][h]
// segment_ids sorted -> segments contiguous. B=64, H=8, D=128, TOTAL=262144.
//
// R2 structure: 32-lane group owns whole rows; lane dq loads features float4
// ONCE and accumulates all 8 heads in registers (R1 loaded each feature row
// 8x, once per head-group -> L1/VMEM-issue bound at 14% VALUBusy).

constexpr int D   = 128;
constexpr int H   = 8;
constexpr int B   = 64;
constexpr int CPS = 32;   // chunk-blocks per segment -> 2048 blocks (8/CU)

// --- kernel 1: find segment start offsets ----------------------------------
__global__ void seg_bounds_kernel(const int* __restrict__ seg, int total,
                                  int* __restrict__ start) {
    int i = blockIdx.x * blockDim.x + threadIdx.x;
    if (i >= total) return;
    int s = seg[i];
    if (i == 0) {
        for (int b = 0; b <= s; ++b) start[b] = 0;
    } else {
        int p = seg[i - 1];
        for (int b = p + 1; b <= s; ++b) start[b] = i;
    }
    if (i == total - 1) {
        for (int b = s + 1; b <= B; ++b) start[b] = total;
    }
}

// --- kernel 2: accumulate into d_out (pre-zeroed) ---------------------------
// 256 threads = 8 groups x 32 lanes. Group g processes rows r0+g, r0+g+8, ...
// Lane dq holds acc[h].xyzw for dims 4*dq..4*dq+3, all 8 heads.
__global__ __launch_bounds__(256) void accum_kernel(
        const float4* __restrict__ F,     // features as float4, 32 per row
        const float4* __restrict__ A4,    // att as float4, 2 per row
        const int*    __restrict__ start, // B+1
        float* __restrict__ out) {        // [B*H*D sums | B*H wsums]
    const int b  = blockIdx.x / CPS;
    const int c  = blockIdx.x % CPS;
    const int s0 = start[b], s1 = start[b + 1];
    const int n  = s1 - s0;
    const int chunk = (n + CPS - 1) / CPS;
    const int r0 = s0 + c * chunk;
    const int r1 = min(r0 + chunk, s1);
    if (r0 >= r1) return;   // uniform across block (no divergent syncthreads)

    const int t  = threadIdx.x;
    const int dq = t & 31;   // float4 slot within row
    const int g  = t >> 5;   // row group 0..7

    float4 acc[8];
    #pragma unroll
    for (int h = 0; h < 8; ++h) acc[h] = make_float4(0.f, 0.f, 0.f, 0.f);
    float4 wa = make_float4(0.f, 0.f, 0.f, 0.f);  // wsum heads 0..3
    float4 wb = make_float4(0.f, 0.f, 0.f, 0.f);  // wsum heads 4..7

    #pragma unroll 2
    for (int i = r0 + g; i < r1; i += 8) {
        float4 f  = F[i * (D / 4) + dq];
        float4 a0 = A4[i * 2 + 0];        // broadcast within group (same addr)
        float4 a1 = A4[i * 2 + 1];
        acc[0].x = fmaf(f.x, a0.x, acc[0].x); acc[0].y = fmaf(f.y, a0.x, acc[0].y);
        acc[0].z = fmaf(f.z, a0.x, acc[0].z); acc[0].w = fmaf(f.w, a0.x, acc[0].w);
        acc[1].x = fmaf(f.x, a0.y, acc[1].x); acc[1].y = fmaf(f.y, a0.y, acc[1].y);
        acc[1].z = fmaf(f.z, a0.y, acc[1].z); acc[1].w = fmaf(f.w, a0.y, acc[1].w);
        acc[2].x = fmaf(f.x, a0.z, acc[2].x); acc[2].y = fmaf(f.y, a0.z, acc[2].y);
        acc[2].z = fmaf(f.z, a0.z, acc[2].z); acc[2].w = fmaf(f.w, a0.z, acc[2].w);
        acc[3].x = fmaf(f.x, a0.w, acc[3].x); acc[3].y = fmaf(f.y, a0.w, acc[3].y);
        acc[3].z = fmaf(f.z, a0.w, acc[3].z); acc[3].w = fmaf(f.w, a0.w, acc[3].w);
        acc[4].x = fmaf(f.x, a1.x, acc[4].x); acc[4].y = fmaf(f.y, a1.x, acc[4].y);
        acc[4].z = fmaf(f.z, a1.x, acc[4].z); acc[4].w = fmaf(f.w, a1.x, acc[4].w);
        acc[5].x = fmaf(f.x, a1.y, acc[5].x); acc[5].y = fmaf(f.y, a1.y, acc[5].y);
        acc[5].z = fmaf(f.z, a1.y, acc[5].z); acc[5].w = fmaf(f.w, a1.y, acc[5].w);
        acc[6].x = fmaf(f.x, a1.z, acc[6].x); acc[6].y = fmaf(f.y, a1.z, acc[6].y);
        acc[6].z = fmaf(f.z, a1.z, acc[6].z); acc[6].w = fmaf(f.w, a1.z, acc[6].w);
        acc[7].x = fmaf(f.x, a1.w, acc[7].x); acc[7].y = fmaf(f.y, a1.w, acc[7].y);
        acc[7].z = fmaf(f.z, a1.w, acc[7].z); acc[7].w = fmaf(f.w, a1.w, acc[7].w);
        wa.x += a0.x; wa.y += a0.y; wa.z += a0.z; wa.w += a0.w;
        wb.x += a1.x; wb.y += a1.y; wb.z += a1.z; wb.w += a1.w;
    }

    // ---- reduce the 8 groups -----------------------------------------------
    // step 1: within each wave64, combine group 2j+1 into 2j via shfl_down(32)
    #pragma unroll
    for (int h = 0; h < 8; ++h) {
        acc[h].x += __shfl_down(acc[h].x, 32);
        acc[h].y += __shfl_down(acc[h].y, 32);
        acc[h].z += __shfl_down(acc[h].z, 32);
        acc[h].w += __shfl_down(acc[h].w, 32);
    }
    wa.x += __shfl_down(wa.x, 32); wa.y += __shfl_down(wa.y, 32);
    wa.z += __shfl_down(wa.z, 32); wa.w += __shfl_down(wa.w, 32);
    wb.x += __shfl_down(wb.x, 32); wb.y += __shfl_down(wb.y, 32);
    wb.z += __shfl_down(wb.z, 32); wb.w += __shfl_down(wb.w, 32);

    // step 2: waves 1..3 park partials in LDS (stride 41: 9,41 coprime w/ 32
    // -> conflict-free), wave 0 sums them and flushes once.
    __shared__ float red[96][41];
    const int lane = t & 63;
    const int wv   = t >> 6;
    if (wv > 0 && lane < 32) {
        float* r = red[(wv - 1) * 32 + lane];
        #pragma unroll
        for (int h = 0; h < 8; ++h) {
            r[h * 4 + 0] = acc[h].x; r[h * 4 + 1] = acc[h].y;
            r[h * 4 + 2] = acc[h].z; r[h * 4 + 3] = acc[h].w;
        }
        r[32] = wa.x; r[33] = wa.y; r[34] = wa.z; r[35] = wa.w;
        r[36] = wb.x; r[37] = wb.y; r[38] = wb.z; r[39] = wb.w;
    }
    __syncthreads();
    if (wv == 0 && lane < 32) {
        #pragma unroll
        for (int j = 0; j < 3; ++j) {
            const float* r = red[j * 32 + lane];
            #pragma unroll
            for (int h = 0; h < 8; ++h) {
                acc[h].x += r[h * 4 + 0]; acc[h].y += r[h * 4 + 1];
                acc[h].z += r[h * 4 + 2]; acc[h].w += r[h * 4 + 3];
            }
            wa.x += r[32]; wa.y += r[33]; wa.z += r[34]; wa.w += r[35];
            wb.x += r[36]; wb.y += r[37]; wb.z += r[38]; wb.w += r[39];
        }
        #pragma unroll
        for (int h = 0; h < 8; ++h) {
            float* o = out + (b * H + h) * D + lane * 4;
            atomicAdd(o + 0, acc[h].x); atomicAdd(o + 1, acc[h].y);
            atomicAdd(o + 2, acc[h].z); atomicAdd(o + 3, acc[h].w);
        }
        if (lane == 0) {   // all 32 lanes hold identical wa/wb
            float* ow = out + B * H * D + b * H;
            atomicAdd(ow + 0, wa.x); atomicAdd(ow + 1, wa.y);
            atomicAdd(ow + 2, wa.z); atomicAdd(ow + 3, wa.w);
            atomicAdd(ow + 4, wb.x); atomicAdd(ow + 5, wb.y);
            atomicAdd(ow + 6, wb.z); atomicAdd(ow + 7, wb.w);
        }
    }
}

// --- kernel 3: divide, where(denom==0,0), NaN->1e-5 -------------------------
__global__ void finalize_kernel(float* __restrict__ out) {
    int idx = blockIdx.x * blockDim.x + threadIdx.x;
    if (idx >= B * H * D) return;
    int   bh    = idx >> 7;                 // b*H + h
    float denom = out[B * H * D + bh];
    float v     = out[idx];
    float r     = (denom == 0.0f) ? 0.0f : v / denom;
    if (isnan(r)) r = 1e-5f;
    out[idx] = r;
}

extern "C" void kernel_launch(void* const* d_in, const int* in_sizes, int n_in,
                              void* d_out, int out_size, void* d_ws, size_t ws_size,
                              hipStream_t stream) {
    const float* features = (const float*)d_in[0];
    const float* att      = (const float*)d_in[1];
    const int*   seg      = (const int*)d_in[2];
    const int    total    = in_sizes[2];

    int*   start = (int*)d_ws;          // B+1 ints of scratch
    float* out   = (float*)d_out;

    hipMemsetAsync(d_out, 0, (size_t)out_size * sizeof(float), stream);

    seg_bounds_kernel<<<(total + 255) / 256, 256, 0, stream>>>(seg, total, start);
    accum_kernel<<<B * CPS, 256, 0, stream>>>(
        (const float4*)features, (const float4*)att, start, out);
    finalize_kernel<<<(B * H * D + 255) / 256, 256, 0, stream>>>(out);
}

// Round 4
// 48.703 us; speedup vs baseline: 1.7764x; 1.6513x over previous
//
#include <hip/hip_runtime.h>

// Segment-wise attention-weighted mean.
//   avg[b][h][d]      = sum_{i in seg b} features[i][d]*att[i][h] / sum att[i][h]
//   weights_sum[b][h] = sum_{i in seg b} att[i][h]
// B=64, H=8, D=128, TOTAL=262144, segment_ids sorted.
//
// R3: R1/R2 both ~100us with VALU<15%, HBM<15% -> wait-bound on the shared
// 2.1M contended f32 atomics (32 blocks x same 1032 addrs per segment).
// Replace atomic flush with per-block partials in d_ws (zero contention),
// then a fused reduce+divide kernel. Atomic path kept as ws_size fallback.

constexpr int D       = 128;
constexpr int H       = 8;
constexpr int B       = 64;
constexpr int CPS     = 32;            // chunk-blocks per segment -> 2048 blocks
constexpr int PSTRIDE = H * D + H;     // 1032 floats per partial record

// --- kernel 1: segment start offsets ----------------------------------------
__global__ void seg_bounds_kernel(const int* __restrict__ seg, int total,
                                  int* __restrict__ start) {
    int i = blockIdx.x * blockDim.x + threadIdx.x;
    if (i >= total) return;
    int s = seg[i];
    if (i == 0) {
        for (int b = 0; b <= s; ++b) start[b] = 0;
    } else {
        int p = seg[i - 1];
        for (int b = p + 1; b <= s; ++b) start[b] = i;
    }
    if (i == total - 1) {
        for (int b = s + 1; b <= B; ++b) start[b] = total;
    }
}

// --- kernel 2: accumulate; flush to partials (two-stage) or atomics --------
// 256 threads = 8 groups x 32 lanes; per k-step the block reads one contiguous
// 4KB slab of features. Lane dq accumulates all 8 heads for dims 4dq..4dq+3.
template <bool TWO_STAGE>
__global__ __launch_bounds__(256) void accum_kernel(
        const float4* __restrict__ F,     // features as float4, 32 per row
        const float4* __restrict__ A4,    // att as float4, 2 per row
        const int*    __restrict__ start, // B+1
        float* __restrict__ dst) {        // partials | out accumulators
    const int b  = blockIdx.x / CPS;
    const int c  = blockIdx.x % CPS;
    const int s0 = start[b], s1 = start[b + 1];
    const int n  = s1 - s0;
    const int chunk = (n + CPS - 1) / CPS;
    const int r0 = s0 + c * chunk;
    const int r1 = min(r0 + chunk, s1);
    // no early return: empty chunks must still write zero partials

    const int t  = threadIdx.x;
    const int dq = t & 31;   // float4 slot within row
    const int g  = t >> 5;   // row group 0..7

    float4 acc[8];
    #pragma unroll
    for (int h = 0; h < 8; ++h) acc[h] = make_float4(0.f, 0.f, 0.f, 0.f);
    float4 wa = make_float4(0.f, 0.f, 0.f, 0.f);
    float4 wb = make_float4(0.f, 0.f, 0.f, 0.f);

    #pragma unroll 2
    for (int i = r0 + g; i < r1; i += 8) {
        float4 f  = F[i * (D / 4) + dq];
        float4 a0 = A4[i * 2 + 0];
        float4 a1 = A4[i * 2 + 1];
        acc[0].x = fmaf(f.x, a0.x, acc[0].x); acc[0].y = fmaf(f.y, a0.x, acc[0].y);
        acc[0].z = fmaf(f.z, a0.x, acc[0].z); acc[0].w = fmaf(f.w, a0.x, acc[0].w);
        acc[1].x = fmaf(f.x, a0.y, acc[1].x); acc[1].y = fmaf(f.y, a0.y, acc[1].y);
        acc[1].z = fmaf(f.z, a0.y, acc[1].z); acc[1].w = fmaf(f.w, a0.y, acc[1].w);
        acc[2].x = fmaf(f.x, a0.z, acc[2].x); acc[2].y = fmaf(f.y, a0.z, acc[2].y);
        acc[2].z = fmaf(f.z, a0.z, acc[2].z); acc[2].w = fmaf(f.w, a0.z, acc[2].w);
        acc[3].x = fmaf(f.x, a0.w, acc[3].x); acc[3].y = fmaf(f.y, a0.w, acc[3].y);
        acc[3].z = fmaf(f.z, a0.w, acc[3].z); acc[3].w = fmaf(f.w, a0.w, acc[3].w);
        acc[4].x = fmaf(f.x, a1.x, acc[4].x); acc[4].y = fmaf(f.y, a1.x, acc[4].y);
        acc[4].z = fmaf(f.z, a1.x, acc[4].z); acc[4].w = fmaf(f.w, a1.x, acc[4].w);
        acc[5].x = fmaf(f.x, a1.y, acc[5].x); acc[5].y = fmaf(f.y, a1.y, acc[5].y);
        acc[5].z = fmaf(f.z, a1.y, acc[5].z); acc[5].w = fmaf(f.w, a1.y, acc[5].w);
        acc[6].x = fmaf(f.x, a1.z, acc[6].x); acc[6].y = fmaf(f.y, a1.z, acc[6].y);
        acc[6].z = fmaf(f.z, a1.z, acc[6].z); acc[6].w = fmaf(f.w, a1.z, acc[6].w);
        acc[7].x = fmaf(f.x, a1.w, acc[7].x); acc[7].y = fmaf(f.y, a1.w, acc[7].y);
        acc[7].z = fmaf(f.z, a1.w, acc[7].z); acc[7].w = fmaf(f.w, a1.w, acc[7].w);
        wa.x += a0.x; wa.y += a0.y; wa.z += a0.z; wa.w += a0.w;
        wb.x += a1.x; wb.y += a1.y; wb.z += a1.z; wb.w += a1.w;
    }

    // ---- reduce the 8 groups: shfl(32) then LDS across the 4 waves --------
    #pragma unroll
    for (int h = 0; h < 8; ++h) {
        acc[h].x += __shfl_down(acc[h].x, 32);
        acc[h].y += __shfl_down(acc[h].y, 32);
        acc[h].z += __shfl_down(acc[h].z, 32);
        acc[h].w += __shfl_down(acc[h].w, 32);
    }
    wa.x += __shfl_down(wa.x, 32); wa.y += __shfl_down(wa.y, 32);
    wa.z += __shfl_down(wa.z, 32); wa.w += __shfl_down(wa.w, 32);
    wb.x += __shfl_down(wb.x, 32); wb.y += __shfl_down(wb.y, 32);
    wb.z += __shfl_down(wb.z, 32); wb.w += __shfl_down(wb.w, 32);

    __shared__ float red[96][41];
    const int lane = t & 63;
    const int wv   = t >> 6;
    if (wv > 0 && lane < 32) {
        float* r = red[(wv - 1) * 32 + lane];
        #pragma unroll
        for (int h = 0; h < 8; ++h) {
            r[h * 4 + 0] = acc[h].x; r[h * 4 + 1] = acc[h].y;
            r[h * 4 + 2] = acc[h].z; r[h * 4 + 3] = acc[h].w;
        }
        r[32] = wa.x; r[33] = wa.y; r[34] = wa.z; r[35] = wa.w;
        r[36] = wb.x; r[37] = wb.y; r[38] = wb.z; r[39] = wb.w;
    }
    __syncthreads();
    if (wv == 0 && lane < 32) {
        #pragma unroll
        for (int j = 0; j < 3; ++j) {
            const float* r = red[j * 32 + lane];
            #pragma unroll
            for (int h = 0; h < 8; ++h) {
                acc[h].x += r[h * 4 + 0]; acc[h].y += r[h * 4 + 1];
                acc[h].z += r[h * 4 + 2]; acc[h].w += r[h * 4 + 3];
            }
            wa.x += r[32]; wa.y += r[33]; wa.z += r[34]; wa.w += r[35];
            wb.x += r[36]; wb.y += r[37]; wb.z += r[38]; wb.w += r[39];
        }
        if (TWO_STAGE) {
            // contention-free: each block owns partial record blockIdx.x
            float4* p = (float4*)(dst + (size_t)blockIdx.x * PSTRIDE);
            #pragma unroll
            for (int h = 0; h < 8; ++h) p[h * 32 + lane] = acc[h];
            if (lane == 0) { p[256] = wa; p[257] = wb; }
        } else {
            #pragma unroll
            for (int h = 0; h < 8; ++h) {
                float* o = dst + (b * H + h) * D + lane * 4;
                atomicAdd(o + 0, acc[h].x); atomicAdd(o + 1, acc[h].y);
                atomicAdd(o + 2, acc[h].z); atomicAdd(o + 3, acc[h].w);
            }
            if (lane == 0) {
                float* ow = dst + B * H * D + b * H;
                atomicAdd(ow + 0, wa.x); atomicAdd(ow + 1, wa.y);
                atomicAdd(ow + 2, wa.z); atomicAdd(ow + 3, wa.w);
                atomicAdd(ow + 4, wb.x); atomicAdd(ow + 5, wb.y);
                atomicAdd(ow + 6, wb.z); atomicAdd(ow + 7, wb.w);
            }
        }
    }
}

// --- kernel 3 (two-stage): reduce partials + divide + nan fixup -------------
// block b: sum 32 partial records; thread t owns j = t+256s, s=0..3 (+wsum t<8)
__global__ __launch_bounds__(256) void reduce_kernel(
        const float* __restrict__ partial, float* __restrict__ out) {
    const int b = blockIdx.x;
    const int t = threadIdx.x;
    const float* pb = partial + (size_t)b * CPS * PSTRIDE;
    float s0 = 0.f, s1 = 0.f, s2 = 0.f, s3 = 0.f, s4 = 0.f;
    for (int c = 0; c < CPS; ++c) {
        const float* pc = pb + c * PSTRIDE;
        s0 += pc[t];
        s1 += pc[t + 256];
        s2 += pc[t + 512];
        s3 += pc[t + 768];
        if (t < 8) s4 += pc[t + 1024];
    }
    __shared__ float wsum[8];
    if (t < 8) wsum[t] = s4;
    __syncthreads();
    float v[4] = {s0, s1, s2, s3};
    #pragma unroll
    for (int s = 0; s < 4; ++s) {
        int   j     = t + 256 * s;
        float denom = wsum[j >> 7];
        float r     = (denom == 0.0f) ? 0.0f : v[s] / denom;
        if (isnan(r)) r = 1e-5f;
        out[b * (H * D) + j] = r;
    }
    if (t < 8) out[B * H * D + b * H + t] = s4;
}

// --- fallback finalize (atomic path) ----------------------------------------
__global__ void finalize_kernel(float* __restrict__ out) {
    int idx = blockIdx.x * blockDim.x + threadIdx.x;
    if (idx >= B * H * D) return;
    int   bh    = idx >> 7;
    float denom = out[B * H * D + bh];
    float v     = out[idx];
    float r     = (denom == 0.0f) ? 0.0f : v / denom;
    if (isnan(r)) r = 1e-5f;
    out[idx] = r;
}

extern "C" void kernel_launch(void* const* d_in, const int* in_sizes, int n_in,
                              void* d_out, int out_size, void* d_ws, size_t ws_size,
                              hipStream_t stream) {
    const float* features = (const float*)d_in[0];
    const float* att      = (const float*)d_in[1];
    const int*   seg      = (const int*)d_in[2];
    const int    total    = in_sizes[2];

    int*   start   = (int*)d_ws;                         // B+1 ints
    float* partial = (float*)((char*)d_ws + 512);        // 16B-aligned
    float* out     = (float*)d_out;

    const size_t needed = 512 + (size_t)B * CPS * PSTRIDE * sizeof(float);

    seg_bounds_kernel<<<(total + 255) / 256, 256, 0, stream>>>(seg, total, start);

    if (ws_size >= needed) {
        accum_kernel<true><<<B * CPS, 256, 0, stream>>>(
            (const float4*)features, (const float4*)att, start, partial);
        reduce_kernel<<<B, 256, 0, stream>>>(partial, out);
    } else {
        hipMemsetAsync(d_out, 0, (size_t)out_size * sizeof(float), stream);
        accum_kernel<false><<<B * CPS, 256, 0, stream>>>(
            (const float4*)features, (const float4*)att, start, out);
        finalize_kernel<<<(B * H * D + 255) / 256, 256, 0, stream>>>(out);
    }
}

// Round 5
// 42.205 us; speedup vs baseline: 2.0499x; 1.1540x over previous
//
#include <hip/hip_runtime.h>

// Segment-wise attention-weighted mean.
//   avg[b][h][d]      = sum_{i in seg b} features[i][d]*att[i][h] / sum att[i][h]
//   weights_sum[b][h] = sum_{i in seg b} att[i][h]
// B=64, H=8, D=128, TOTAL=262144, segment_ids sorted.
//
// R4: two-stage (contention-free partials) fixed the atomic wait-bound
// (80->48.7us). R5: reduce stage gets 8x parallelism (512 blocks, one per
// (b,h), coalesced + unrolled); accum unchanged (est. ~28us, near BW floor).

constexpr int D       = 128;
constexpr int H       = 8;
constexpr int B       = 64;
constexpr int CPS     = 32;            // chunk-blocks per segment -> 2048 blocks
constexpr int PSTRIDE = H * D + H;     // 1032 floats per partial record

// --- kernel 1: segment start offsets ----------------------------------------
__global__ void seg_bounds_kernel(const int* __restrict__ seg, int total,
                                  int* __restrict__ start) {
    int i = blockIdx.x * blockDim.x + threadIdx.x;
    if (i >= total) return;
    int s = seg[i];
    if (i == 0) {
        for (int b = 0; b <= s; ++b) start[b] = 0;
    } else {
        int p = seg[i - 1];
        for (int b = p + 1; b <= s; ++b) start[b] = i;
    }
    if (i == total - 1) {
        for (int b = s + 1; b <= B; ++b) start[b] = total;
    }
}

// --- kernel 2: accumulate; flush to partials (two-stage) or atomics --------
// 256 threads = 8 groups x 32 lanes; per step the block reads one contiguous
// 4KB slab of features. Lane dq accumulates all 8 heads for dims 4dq..4dq+3.
template <bool TWO_STAGE>
__global__ __launch_bounds__(256) void accum_kernel(
        const float4* __restrict__ F,     // features as float4, 32 per row
        const float4* __restrict__ A4,    // att as float4, 2 per row
        const int*    __restrict__ start, // B+1
        float* __restrict__ dst) {        // partials | out accumulators
    const int b  = blockIdx.x / CPS;
    const int c  = blockIdx.x % CPS;
    const int s0 = start[b], s1 = start[b + 1];
    const int n  = s1 - s0;
    const int chunk = (n + CPS - 1) / CPS;
    const int r0 = s0 + c * chunk;
    const int r1 = min(r0 + chunk, s1);
    // no early return: empty chunks must still write zero partials

    const int t  = threadIdx.x;
    const int dq = t & 31;   // float4 slot within row
    const int g  = t >> 5;   // row group 0..7

    float4 acc[8];
    #pragma unroll
    for (int h = 0; h < 8; ++h) acc[h] = make_float4(0.f, 0.f, 0.f, 0.f);
    float4 wa = make_float4(0.f, 0.f, 0.f, 0.f);
    float4 wb = make_float4(0.f, 0.f, 0.f, 0.f);

    #pragma unroll 4
    for (int i = r0 + g; i < r1; i += 8) {
        float4 f  = F[i * (D / 4) + dq];
        float4 a0 = A4[i * 2 + 0];
        float4 a1 = A4[i * 2 + 1];
        acc[0].x = fmaf(f.x, a0.x, acc[0].x); acc[0].y = fmaf(f.y, a0.x, acc[0].y);
        acc[0].z = fmaf(f.z, a0.x, acc[0].z); acc[0].w = fmaf(f.w, a0.x, acc[0].w);
        acc[1].x = fmaf(f.x, a0.y, acc[1].x); acc[1].y = fmaf(f.y, a0.y, acc[1].y);
        acc[1].z = fmaf(f.z, a0.y, acc[1].z); acc[1].w = fmaf(f.w, a0.y, acc[1].w);
        acc[2].x = fmaf(f.x, a0.z, acc[2].x); acc[2].y = fmaf(f.y, a0.z, acc[2].y);
        acc[2].z = fmaf(f.z, a0.z, acc[2].z); acc[2].w = fmaf(f.w, a0.z, acc[2].w);
        acc[3].x = fmaf(f.x, a0.w, acc[3].x); acc[3].y = fmaf(f.y, a0.w, acc[3].y);
        acc[3].z = fmaf(f.z, a0.w, acc[3].z); acc[3].w = fmaf(f.w, a0.w, acc[3].w);
        acc[4].x = fmaf(f.x, a1.x, acc[4].x); acc[4].y = fmaf(f.y, a1.x, acc[4].y);
        acc[4].z = fmaf(f.z, a1.x, acc[4].z); acc[4].w = fmaf(f.w, a1.x, acc[4].w);
        acc[5].x = fmaf(f.x, a1.y, acc[5].x); acc[5].y = fmaf(f.y, a1.y, acc[5].y);
        acc[5].z = fmaf(f.z, a1.y, acc[5].z); acc[5].w = fmaf(f.w, a1.y, acc[5].w);
        acc[6].x = fmaf(f.x, a1.z, acc[6].x); acc[6].y = fmaf(f.y, a1.z, acc[6].y);
        acc[6].z = fmaf(f.z, a1.z, acc[6].z); acc[6].w = fmaf(f.w, a1.z, acc[6].w);
        acc[7].x = fmaf(f.x, a1.w, acc[7].x); acc[7].y = fmaf(f.y, a1.w, acc[7].y);
        acc[7].z = fmaf(f.z, a1.w, acc[7].z); acc[7].w = fmaf(f.w, a1.w, acc[7].w);
        wa.x += a0.x; wa.y += a0.y; wa.z += a0.z; wa.w += a0.w;
        wb.x += a1.x; wb.y += a1.y; wb.z += a1.z; wb.w += a1.w;
    }

    // ---- reduce the 8 groups: shfl(32) then LDS across the 4 waves --------
    #pragma unroll
    for (int h = 0; h < 8; ++h) {
        acc[h].x += __shfl_down(acc[h].x, 32);
        acc[h].y += __shfl_down(acc[h].y, 32);
        acc[h].z += __shfl_down(acc[h].z, 32);
        acc[h].w += __shfl_down(acc[h].w, 32);
    }
    wa.x += __shfl_down(wa.x, 32); wa.y += __shfl_down(wa.y, 32);
    wa.z += __shfl_down(wa.z, 32); wa.w += __shfl_down(wa.w, 32);
    wb.x += __shfl_down(wb.x, 32); wb.y += __shfl_down(wb.y, 32);
    wb.z += __shfl_down(wb.z, 32); wb.w += __shfl_down(wb.w, 32);

    __shared__ float red[96][41];
    const int lane = t & 63;
    const int wv   = t >> 6;
    if (wv > 0 && lane < 32) {
        float* r = red[(wv - 1) * 32 + lane];
        #pragma unroll
        for (int h = 0; h < 8; ++h) {
            r[h * 4 + 0] = acc[h].x; r[h * 4 + 1] = acc[h].y;
            r[h * 4 + 2] = acc[h].z; r[h * 4 + 3] = acc[h].w;
        }
        r[32] = wa.x; r[33] = wa.y; r[34] = wa.z; r[35] = wa.w;
        r[36] = wb.x; r[37] = wb.y; r[38] = wb.z; r[39] = wb.w;
    }
    __syncthreads();
    if (wv == 0 && lane < 32) {
        #pragma unroll
        for (int j = 0; j < 3; ++j) {
            const float* r = red[j * 32 + lane];
            #pragma unroll
            for (int h = 0; h < 8; ++h) {
                acc[h].x += r[h * 4 + 0]; acc[h].y += r[h * 4 + 1];
                acc[h].z += r[h * 4 + 2]; acc[h].w += r[h * 4 + 3];
            }
            wa.x += r[32]; wa.y += r[33]; wa.z += r[34]; wa.w += r[35];
            wb.x += r[36]; wb.y += r[37]; wb.z += r[38]; wb.w += r[39];
        }
        if (TWO_STAGE) {
            // contention-free: each block owns partial record blockIdx.x
            float4* p = (float4*)(dst + (size_t)blockIdx.x * PSTRIDE);
            #pragma unroll
            for (int h = 0; h < 8; ++h) p[h * 32 + lane] = acc[h];
            if (lane == 0) { p[256] = wa; p[257] = wb; }
        } else {
            #pragma unroll
            for (int h = 0; h < 8; ++h) {
                float* o = dst + (b * H + h) * D + lane * 4;
                atomicAdd(o + 0, acc[h].x); atomicAdd(o + 1, acc[h].y);
                atomicAdd(o + 2, acc[h].z); atomicAdd(o + 3, acc[h].w);
            }
            if (lane == 0) {
                float* ow = dst + B * H * D + b * H;
                atomicAdd(ow + 0, wa.x); atomicAdd(ow + 1, wa.y);
                atomicAdd(ow + 2, wa.z); atomicAdd(ow + 3, wa.w);
                atomicAdd(ow + 4, wb.x); atomicAdd(ow + 5, wb.y);
                atomicAdd(ow + 6, wb.z); atomicAdd(ow + 7, wb.w);
            }
        }
    }
}

// --- kernel 3 (two-stage): reduce partials + divide + nan fixup -------------
// R5: one block per (b,h) -> 512 blocks. Thread t sums dim t over 32 records
// (coalesced 512B per step, unroll 8 for MLP). Wave 0 reduces wsum.
__global__ __launch_bounds__(128) void reduce_kernel(
        const float* __restrict__ partial, float* __restrict__ out) {
    const int blk = blockIdx.x;          // b*H + h
    const int b   = blk >> 3;
    const int h   = blk & 7;
    const int t   = threadIdx.x;

    const float* base = partial + (size_t)b * CPS * PSTRIDE + h * D + t;
    float s = 0.f;
    #pragma unroll 8
    for (int c = 0; c < CPS; ++c) s += base[c * PSTRIDE];

    float w = 0.f;
    if (t < 32)
        w = partial[((size_t)(b * CPS + t)) * PSTRIDE + H * D + h];
    if (t < 64) {
        #pragma unroll
        for (int off = 32; off >= 1; off >>= 1) w += __shfl_down(w, off);
    }
    __shared__ float wsh;
    if (t == 0) wsh = w;
    __syncthreads();

    const float denom = wsh;
    float r = (denom == 0.0f) ? 0.0f : s / denom;
    if (isnan(r)) r = 1e-5f;
    out[blk * D + t] = r;
    if (t == 0) out[B * H * D + blk] = denom;
}

// --- fallback finalize (atomic path) ----------------------------------------
__global__ void finalize_kernel(float* __restrict__ out) {
    int idx = blockIdx.x * blockDim.x + threadIdx.x;
    if (idx >= B * H * D) return;
    int   bh    = idx >> 7;
    float denom = out[B * H * D + bh];
    float v     = out[idx];
    float r     = (denom == 0.0f) ? 0.0f : v / denom;
    if (isnan(r)) r = 1e-5f;
    out[idx] = r;
}

extern "C" void kernel_launch(void* const* d_in, const int* in_sizes, int n_in,
                              void* d_out, int out_size, void* d_ws, size_t ws_size,
                              hipStream_t stream) {
    const float* features = (const float*)d_in[0];
    const float* att      = (const float*)d_in[1];
    const int*   seg      = (const int*)d_in[2];
    const int    total    = in_sizes[2];

    int*   start   = (int*)d_ws;                         // B+1 ints
    float* partial = (float*)((char*)d_ws + 512);        // 16B-aligned
    float* out     = (float*)d_out;

    const size_t needed = 512 + (size_t)B * CPS * PSTRIDE * sizeof(float);

    seg_bounds_kernel<<<(total + 255) / 256, 256, 0, stream>>>(seg, total, start);

    if (ws_size >= needed) {
        accum_kernel<true><<<B * CPS, 256, 0, stream>>>(
            (const float4*)features, (const float4*)att, start, partial);
        reduce_kernel<<<B * H, 128, 0, stream>>>(partial, out);
    } else {
        hipMemsetAsync(d_out, 0, (size_t)out_size * sizeof(float), stream);
        accum_kernel<false><<<B * CPS, 256, 0, stream>>>(
            (const float4*)features, (const float4*)att, start, out);
        finalize_kernel<<<(B * H * D + 255) / 256, 256, 0, stream>>>(out);
    }
}